// Round 5
// baseline (785.626 us; speedup 1.0000x reference)
//
#include <hip/hip_runtime.h>
#include <math.h>

#define RAD 20
#define KLEN 41
#define NH 1024
#define NW 2048
#define NHW (NH * NW)

// ---- Compile-time Gaussian-derivative weights (fp64, matches numpy) ----
struct KW { float w[KLEN]; };
constexpr double cexp_neg(double u) {  // exp(-u), 0 <= u <= 0.5
  double term = 1.0, sum = 1.0;
  for (int k = 1; k < 30; ++k) { term *= (-u) / (double)k; sum += term; }
  return sum;
}
constexpr KW make_kw() {
  KW r{};
  double ph[KLEN] = {};
  double s = 0.0;
  for (int i = 0; i < KLEN; ++i) {
    double d = (double)(i - RAD);
    double e = cexp_neg(d * d / 800.0);
    e = e * e; e = e * e; e = e * e; e = e * e;  // ^16
    ph[i] = e; s += e;
  }
  for (int i = 0; i < KLEN; ++i) {
    double d = (double)(i - RAD);
    r.w[i] = (float)((-d / 25.0) * (ph[i] / s) / 2.27);
  }
  return r;
}
static constexpr KW KWC = make_kw();

// 48-float window in 12 NAMED float4s; selection folds post-unroll.
#define GETC(A, c) ((c) == 0 ? (A).x : (c) == 1 ? (A).y : (c) == 2 ? (A).z : (A).w)
#define W12(k)                                    \
  ((k) < 4    ? GETC(a0, (k) & 3)                 \
   : (k) < 8  ? GETC(a1, (k) & 3)                 \
   : (k) < 12 ? GETC(a2, (k) & 3)                 \
   : (k) < 16 ? GETC(a3, (k) & 3)                 \
   : (k) < 20 ? GETC(a4, (k) & 3)                 \
   : (k) < 24 ? GETC(a5, (k) & 3)                 \
   : (k) < 28 ? GETC(a6, (k) & 3)                 \
   : (k) < 32 ? GETC(a7, (k) & 3)                 \
   : (k) < 36 ? GETC(a8, (k) & 3)                 \
   : (k) < 40 ? GETC(a9, (k) & 3)                 \
   : (k) < 44 ? GETC(a10, (k) & 3)                \
              : GETC(a11, (k) & 3))

// m_0 numerator: sum over pixels of ||m||_F (fp32 sqrt, fp64 accumulate).
__global__ __launch_bounds__(256) void k_reduce(const float* __restrict__ y,
                                                double* __restrict__ acc) {
  const int tid = blockIdx.x * blockDim.x + threadIdx.x;
  const int stride = gridDim.x * blockDim.x;
  double local = 0.0;
  for (int i = tid; i < NHW; i += stride) {
    float a = y[i];
    float b = y[i + NHW];
    float c = y[i + 2 * (size_t)NHW];
    float d = y[i + 3 * (size_t)NHW];
    local += (double)sqrtf(a * a + b * b + c * c + d * d);
  }
#pragma unroll
  for (int off = 32; off > 0; off >>= 1) local += __shfl_down(local, off, 64);
  __shared__ double smem[4];
  const int lane = threadIdx.x & 63;
  const int wid = threadIdx.x >> 6;
  if (lane == 0) smem[wid] = local;
  __syncthreads();
  if (threadIdx.x == 0) {
    double s = smem[0] + smem[1] + smem[2] + smem[3];
    atomicAdd(acc, s);
  }
}

// diffX: reflect pad along W. One block per row; 256 thr x 8 px = 2048.
// 12 batched float4 loads into named regs; launch_bounds(256,4) -> 128 VGPR
// budget so the compiler can keep all loads in flight (round-4 lesson: 52
// VGPRs forced load->wait->consume serialization at ~300 cyc/load).
__global__ __launch_bounds__(256, 4) void k_dx(const float* __restrict__ y,
                                               const float* __restrict__ v,
                                               float* __restrict__ ws) {
  const int t = threadIdx.x;
  const int row = blockIdx.x;
  const int ch = blockIdx.y;  // 0..6 -> y0..y4, v0, v1
  const float* src = (ch < 5) ? (y + (size_t)ch * NHW) : (v + (size_t)(ch - 5) * NHW);
  const float* rp = src + (size_t)row * NW;
  const int x0 = t * 8;  // output octet base; window = [x0-20, x0+27]

  float4 a0, a1, a2, a3, a4, a5, a6, a7, a8, a9, a10, a11;
  if (t >= 3 && t <= 252) {
    const float4* p = (const float4*)(rp + x0 - RAD);  // (8t-20)%4==0 -> 16B aligned
    a0 = p[0]; a1 = p[1]; a2 = p[2]; a3 = p[3]; a4 = p[4]; a5 = p[5];
    a6 = p[6]; a7 = p[7]; a8 = p[8]; a9 = p[9]; a10 = p[10]; a11 = p[11];
  } else {
#define RIDX(q) ((q) < 0 ? -(q) : ((q) >= NW ? 2 * NW - 2 - (q) : (q)))
#define FILL4(A, b)        \
  A.x = rp[RIDX((b) + 0)]; \
  A.y = rp[RIDX((b) + 1)]; \
  A.z = rp[RIDX((b) + 2)]; \
  A.w = rp[RIDX((b) + 3)];
    const int b0 = x0 - RAD;
    FILL4(a0, b0 + 0)  FILL4(a1, b0 + 4)  FILL4(a2, b0 + 8)
    FILL4(a3, b0 + 12) FILL4(a4, b0 + 16) FILL4(a5, b0 + 20)
    FILL4(a6, b0 + 24) FILL4(a7, b0 + 28) FILL4(a8, b0 + 32)
    FILL4(a9, b0 + 36) FILL4(a10, b0 + 40) FILL4(a11, b0 + 44)
  }

  float4 r0, r1;
  r0.x = r0.y = r0.z = r0.w = 0.f;
  r1.x = r1.y = r1.z = r1.w = 0.f;
#pragma unroll
  for (int j = 0; j < KLEN; ++j) {
    const float w = KWC.w[j];
    r0.x = fmaf(W12(j + 0), w, r0.x);
    r0.y = fmaf(W12(j + 1), w, r0.y);
    r0.z = fmaf(W12(j + 2), w, r0.z);
    r0.w = fmaf(W12(j + 3), w, r0.w);
    r1.x = fmaf(W12(j + 4), w, r1.x);
    r1.y = fmaf(W12(j + 5), w, r1.y);
    r1.z = fmaf(W12(j + 6), w, r1.z);
    r1.w = fmaf(W12(j + 7), w, r1.w);
  }
  float4* dst = (float4*)(ws + (size_t)(7 + ch) * NHW + (size_t)row * NW + x0);
  dst[0] = r0;
  dst[1] = r1;
}

// diffY: wrap pad along H. Lanes contiguous in x; 48 batched coalesced row
// loads into named regs; 8 outputs (consecutive rows) per thread.
__global__ __launch_bounds__(256, 4) void k_dy(const float* __restrict__ y,
                                               const float* __restrict__ v,
                                               float* __restrict__ ws) {
  const int x = blockIdx.x * 256 + threadIdx.x;
  const int y0 = blockIdx.y * 8;
  const int ch = blockIdx.z;
  const float* src = (ch < 5) ? (y + (size_t)ch * NHW) : (v + (size_t)(ch - 5) * NHW);

#define ROWLD(i) src[(size_t)(((y0 - RAD + (i)) + NH) & (NH - 1)) * NW + x]
#define LOAD4(A, b)      \
  A.x = ROWLD((b) + 0);  \
  A.y = ROWLD((b) + 1);  \
  A.z = ROWLD((b) + 2);  \
  A.w = ROWLD((b) + 3);
  float4 a0, a1, a2, a3, a4, a5, a6, a7, a8, a9, a10, a11;
  LOAD4(a0, 0)  LOAD4(a1, 4)  LOAD4(a2, 8)  LOAD4(a3, 12)
  LOAD4(a4, 16) LOAD4(a5, 20) LOAD4(a6, 24) LOAD4(a7, 28)
  LOAD4(a8, 32) LOAD4(a9, 36) LOAD4(a10, 40) LOAD4(a11, 44)

  float4 r0, r1;
  r0.x = r0.y = r0.z = r0.w = 0.f;
  r1.x = r1.y = r1.z = r1.w = 0.f;
#pragma unroll
  for (int j = 0; j < KLEN; ++j) {
    const float w = KWC.w[j];
    r0.x = fmaf(W12(j + 0), w, r0.x);
    r0.y = fmaf(W12(j + 1), w, r0.y);
    r0.z = fmaf(W12(j + 2), w, r0.z);
    r0.w = fmaf(W12(j + 3), w, r0.w);
    r1.x = fmaf(W12(j + 4), w, r1.x);
    r1.y = fmaf(W12(j + 5), w, r1.y);
    r1.z = fmaf(W12(j + 6), w, r1.z);
    r1.w = fmaf(W12(j + 7), w, r1.w);
  }
  float* dst = ws + (size_t)ch * NHW + (size_t)y0 * NW + x;
  dst[0] = r0.x;
  dst[(size_t)NW] = r0.y;
  dst[2 * (size_t)NW] = r0.z;
  dst[3 * (size_t)NW] = r0.w;
  dst[4 * (size_t)NW] = r1.x;
  dst[5 * (size_t)NW] = r1.y;
  dst[6 * (size_t)NW] = r1.z;
  dst[7 * (size_t)NW] = r1.w;
}

// Pointwise 2x2 tensor algebra. ws planes: [0..6]=dY(ch), [7..13]=dX(ch).
__global__ __launch_bounds__(256) void k_final(
    const float* __restrict__ y, const float* __restrict__ v,
    const float* __restrict__ gds, const float* __restrict__ cadc,
    const float* __restrict__ myoc, const float* __restrict__ ws,
    const double* __restrict__ acc, float* __restrict__ out) {
  const size_t i = (size_t)blockIdx.x * blockDim.x + threadIdx.x;
  if (i >= NHW) return;

  const float m0 = (float)(acc[0] / (double)NHW);
  const float cad0 = fmaxf(cadc[0], 0.f);
  const float cad1 = fmaxf(cadc[1], 0.f);
  const float cad2 = fmaxf(cadc[2], 0.f);
  const float my0 = fmaxf(myoc[0], 0.f);
  const float my1 = fmaxf(myoc[1], 0.f);
  const float my2 = fmaxf(myoc[2], 0.f);
  const float my3 = fmaxf(myoc[3], 0.f);
  const float my4 = fmaxf(myoc[4], 0.f);

  const float m00 = y[i];
  const float m01 = y[i + (size_t)NHW];
  const float m10 = y[i + 2 * (size_t)NHW];
  const float m11 = y[i + 3 * (size_t)NHW];
  const float c = y[i + 4 * (size_t)NHW];
  const float v0 = v[i];
  const float v1 = v[i + (size_t)NHW];
  const float g = gds[i];

  const float dY_m00 = ws[i];
  const float dY_m01 = ws[i + (size_t)NHW];
  const float dY_m10 = ws[i + 2 * (size_t)NHW];
  const float dY_m11 = ws[i + 3 * (size_t)NHW];
  const float dY_c = ws[i + 4 * (size_t)NHW];
  const float dY_v0 = ws[i + 5 * (size_t)NHW];
  const float dY_v1 = ws[i + 6 * (size_t)NHW];
  const float dX_m00 = ws[i + 7 * (size_t)NHW];
  const float dX_m01 = ws[i + 8 * (size_t)NHW];
  const float dX_m10 = ws[i + 9 * (size_t)NHW];
  const float dX_m11 = ws[i + 10 * (size_t)NHW];
  const float dX_c = ws[i + 11 * (size_t)NHW];
  const float dX_v0 = ws[i + 12 * (size_t)NHW];
  const float dX_v1 = ws[i + 13 * (size_t)NHW];

  // gv[i][j] = d_j v_i ; j=0 -> Y, j=1 -> X
  const float gv00 = dY_v0, gv01 = dX_v0, gv10 = dY_v1, gv11 = dX_v1;
  const float ww = -0.5f * (gv01 - gv10);
  const float E00 = gv00, E11 = gv11;
  const float E01 = 0.5f * (gv01 + gv10);
  const float E10 = E01;

  const float trm = m00 + m11;
  const float dev00 = m00 - 0.5f * trm;
  const float dev01 = m01;
  const float dev10 = m10;
  const float dev11 = m11 - 0.5f * trm;
  const float dmag_sq = dev00 * dev00 + dev01 * dev01 + dev10 * dev10 + dev11 * dev11;
  const float dm = sqrtf(dmag_sq);
  const float dm2 = dm * dm;  // reference squares the sqrt
  const float devE = dev00 * E00 + dev01 * E01 + dev10 * E10 + dev11 * E11;
  const float sg = (devE > 0.f) ? 1.f : ((devE < 0.f) ? -1.f : 0.f);
  const float coef = sg * devE / dm2;
  const float sc = 0.5f * dm / m0;

  const float Ea00 = (E00 - coef * dev00) * sc;
  const float Ea01 = (E01 - coef * dev01) * sc;
  const float Ea10 = (E10 - coef * dev10) * sc;
  const float Ea11 = (E11 - coef * dev11) * sc;
  const float Ep00 = E00 - Ea00;
  const float Ep01 = E01 - Ea01;
  const float Ep10 = E10 - Ea10;
  const float Ep11 = E11 - Ea11;

  // mE = m*Ep + Ep*m
  const float mE00 = (m00 * Ep00 + m01 * Ep10) + (Ep00 * m00 + Ep01 * m10);
  const float mE01 = (m00 * Ep01 + m01 * Ep11) + (Ep00 * m01 + Ep01 * m11);
  const float mE10 = (m10 * Ep00 + m11 * Ep10) + (Ep10 * m00 + Ep11 * m10);
  const float mE11 = (m10 * Ep01 + m11 * Ep11) + (Ep10 * m01 + Ep11 * m11);

  const float divv = gv00 + gv11;
  const float cdot = -(v0 * dY_c + v1 * dX_c) - cad0 * c + cad1 * c * divv + cad2 * g;

  const float md00 = -(v0 * dY_m00 + v1 * dX_m00) - ww * m10 - ww * m01 - my0 * m00 +
                     my1 * mE00 - my2 * c * mE00 + my3 * trm + my4 * trm * m00;
  const float md01 = -(v0 * dY_m01 + v1 * dX_m01) - ww * m11 + ww * m00 - my0 * m01 +
                     my1 * mE01 - my2 * c * mE01 + my4 * trm * m01;
  const float md10 = -(v0 * dY_m10 + v1 * dX_m10) + ww * m00 - ww * m11 - my0 * m10 +
                     my1 * mE10 - my2 * c * mE10 + my4 * trm * m10;
  const float md11 = -(v0 * dY_m11 + v1 * dX_m11) + ww * m01 + ww * m10 - my0 * m11 +
                     my1 * mE11 - my2 * c * mE11 + my4 * trm * m11;

  out[i] = md00;
  out[i + (size_t)NHW] = md01;
  out[i + 2 * (size_t)NHW] = md10;
  out[i + 3 * (size_t)NHW] = md11;
  out[i + 4 * (size_t)NHW] = cdot;
}

extern "C" void kernel_launch(void* const* d_in, const int* in_sizes, int n_in,
                              void* d_out, int out_size, void* d_ws, size_t ws_size,
                              hipStream_t stream) {
  (void)in_sizes; (void)n_in; (void)out_size; (void)ws_size;
  const float* y = (const float*)d_in[0];
  const float* v = (const float*)d_in[1];
  const float* gds = (const float*)d_in[2];
  const float* cadc = (const float*)d_in[3];
  const float* myoc = (const float*)d_in[4];
  float* out = (float*)d_out;

  double* acc = (double*)d_ws;                       // 8B accumulator
  float* planes = (float*)((char*)d_ws + 512);       // 14 x NHW fp32 planes

  hipMemsetAsync(acc, 0, sizeof(double), stream);
  k_reduce<<<dim3(1024), dim3(256), 0, stream>>>(y, acc);
  k_dx<<<dim3(NH, 7), dim3(256), 0, stream>>>(y, v, planes);
  k_dy<<<dim3(NW / 256, NH / 8, 7), dim3(256), 0, stream>>>(y, v, planes);
  k_final<<<dim3(NHW / 256), dim3(256), 0, stream>>>(y, v, gds, cadc, myoc, planes, acc, out);
}

// Round 6
// 684.616 us; speedup vs baseline: 1.1475x; 1.1475x over previous
//
#include <hip/hip_runtime.h>
#include <math.h>

#define RAD 20
#define KLEN 41
#define NH 1024
#define NW 2048
#define NHW (NH * NW)

// ---- Compile-time Gaussian-derivative weights (fp64, matches numpy) ----
struct KW { float w[KLEN]; };
constexpr double cexp_neg(double u) {  // exp(-u), 0 <= u <= 0.5
  double term = 1.0, sum = 1.0;
  for (int k = 1; k < 30; ++k) { term *= (-u) / (double)k; sum += term; }
  return sum;
}
constexpr KW make_kw() {
  KW r{};
  double ph[KLEN] = {};
  double s = 0.0;
  for (int i = 0; i < KLEN; ++i) {
    double d = (double)(i - RAD);
    double e = cexp_neg(d * d / 800.0);
    e = e * e; e = e * e; e = e * e; e = e * e;  // ^16
    ph[i] = e; s += e;
  }
  for (int i = 0; i < KLEN; ++i) {
    double d = (double)(i - RAD);
    r.w[i] = (float)((-d / 25.0) * (ph[i] / s) / 2.27);
  }
  return r;
}
static constexpr KW KWC = make_kw();

// 48-float window in 12 NAMED float4s; selection folds post-unroll.
#define GETC(A, c) ((c) == 0 ? (A).x : (c) == 1 ? (A).y : (c) == 2 ? (A).z : (A).w)
#define W12(k)                                    \
  ((k) < 4    ? GETC(a0, (k) & 3)                 \
   : (k) < 8  ? GETC(a1, (k) & 3)                 \
   : (k) < 12 ? GETC(a2, (k) & 3)                 \
   : (k) < 16 ? GETC(a3, (k) & 3)                 \
   : (k) < 20 ? GETC(a4, (k) & 3)                 \
   : (k) < 24 ? GETC(a5, (k) & 3)                 \
   : (k) < 28 ? GETC(a6, (k) & 3)                 \
   : (k) < 32 ? GETC(a7, (k) & 3)                 \
   : (k) < 36 ? GETC(a8, (k) & 3)                 \
   : (k) < 40 ? GETC(a9, (k) & 3)                 \
   : (k) < 44 ? GETC(a10, (k) & 3)                \
              : GETC(a11, (k) & 3))

// Shared 8-output FMA core over the a0..a11 window.
#define CONV8(r0, r1)                             \
  _Pragma("unroll")                               \
  for (int j = 0; j < KLEN; ++j) {                \
    const float w = KWC.w[j];                     \
    r0.x = fmaf(W12(j + 0), w, r0.x);             \
    r0.y = fmaf(W12(j + 1), w, r0.y);             \
    r0.z = fmaf(W12(j + 2), w, r0.z);             \
    r0.w = fmaf(W12(j + 3), w, r0.w);             \
    r1.x = fmaf(W12(j + 4), w, r1.x);             \
    r1.y = fmaf(W12(j + 5), w, r1.y);             \
    r1.z = fmaf(W12(j + 6), w, r1.z);             \
    r1.w = fmaf(W12(j + 7), w, r1.w);             \
  }

// m_0 numerator: sum over pixels of ||m||_F (fp32 sqrt, fp64 accumulate).
__global__ __launch_bounds__(256) void k_reduce(const float* __restrict__ y,
                                                double* __restrict__ acc) {
  const int tid = blockIdx.x * blockDim.x + threadIdx.x;
  const int stride = gridDim.x * blockDim.x;
  double local = 0.0;
  for (int i = tid; i < NHW; i += stride) {
    float a = y[i];
    float b = y[i + NHW];
    float c = y[i + 2 * (size_t)NHW];
    float d = y[i + 3 * (size_t)NHW];
    local += (double)sqrtf(a * a + b * b + c * c + d * d);
  }
#pragma unroll
  for (int off = 32; off > 0; off >>= 1) local += __shfl_down(local, off, 64);
  __shared__ double smem[4];
  const int lane = threadIdx.x & 63;
  const int wid = threadIdx.x >> 6;
  if (lane == 0) smem[wid] = local;
  __syncthreads();
  if (threadIdx.x == 0) {
    double s = smem[0] + smem[1] + smem[2] + smem[3];
    atomicAdd(acc, s);
  }
}

// diffX, LDS-staged: one block = one padded row (2088 floats). Staging loads
// are INDEPENDENT dense float4s (latency paid once, batched before barrier);
// compute reads the window from LDS (ds_read_b128, ~120cyc hideable latency).
__global__ __launch_bounds__(256) void k_dx(const float* __restrict__ y,
                                            const float* __restrict__ v,
                                            float* __restrict__ ws) {
  __shared__ float row[NW + 2 * RAD];  // 2088 floats, 16B-aligned base
  const int t = threadIdx.x;
  const int r = blockIdx.x;
  const int ch = blockIdx.y;  // 0..6 -> y0..y4, v0, v1
  const float* src = (ch < 5) ? (y + (size_t)ch * NHW) : (v + (size_t)(ch - 5) * NHW);
  const float* rp = src + (size_t)r * NW;

  // Body: two fully-contiguous 1KB wave loads (float4 at t and t+256).
  const float4* rp4 = (const float4*)rp;
  float4 b0 = rp4[t];
  float4 b1 = rp4[t + 256];
  float4* row4 = (float4*)(row + RAD);  // offset 80B, 16B-aligned
  row4[t] = b0;
  row4[t + 256] = b1;
  // Halo: numpy 'reflect' (no edge repeat).
  if (t < RAD) {
    row[t] = rp[RAD - t];                 // left: padded i -> x[RAD-i]
    row[NW + RAD + t] = rp[NW - 2 - t];   // right: x[NW-2-j]
  }
  __syncthreads();

  // Window for outputs x0=8t..8t+7: padded row[8t .. 8t+47] = 12 float4s.
  const float4* p = (const float4*)(row + 8 * t);  // 32B offsets: aligned
  float4 a0 = p[0], a1 = p[1], a2 = p[2], a3 = p[3], a4 = p[4], a5 = p[5];
  float4 a6 = p[6], a7 = p[7], a8 = p[8], a9 = p[9], a10 = p[10], a11 = p[11];

  float4 r0, r1;
  r0.x = r0.y = r0.z = r0.w = 0.f;
  r1.x = r1.y = r1.z = r1.w = 0.f;
  CONV8(r0, r1)

  float4* dst = (float4*)(ws + (size_t)(7 + ch) * NHW + (size_t)r * NW + 8 * t);
  dst[0] = r0;
  dst[1] = r1;
}

#define TW 64  // k_dy tile width (x)
#define TH 32  // k_dy output rows per block

// diffY, LDS-staged: 64x32-output tile; stage (TH+40)x64 input rows with wrap
// applied at staging (no divergence in compute). Column reads stride TW=64
// floats -> bank = lane%32 -> 2-way alias (free).
__global__ __launch_bounds__(256) void k_dy(const float* __restrict__ y,
                                            const float* __restrict__ v,
                                            float* __restrict__ ws) {
  __shared__ float tile[(TH + 2 * RAD) * TW];  // 72*64 = 18432B
  const int lane = threadIdx.x & 63;
  const int wid = threadIdx.x >> 6;  // 0..3
  const int x0 = blockIdx.x * TW;
  const int yb = blockIdx.y * TH;
  const int ch = blockIdx.z;
  const float* src = (ch < 5) ? (y + (size_t)ch * NHW) : (v + (size_t)(ch - 5) * NHW);

  // Stage 72 rows; 18 independent coalesced 256B wave loads per wave.
#pragma unroll
  for (int k = 0; k < 18; ++k) {
    const int rr = wid + 4 * k;
    const int gy = (yb - RAD + rr + NH) & (NH - 1);  // wrap
    tile[rr * TW + lane] = src[(size_t)gy * NW + x0 + lane];
  }
  __syncthreads();

  // Each wave handles 8 output rows: yb + wid*8 + {0..7} at column x0+lane.
  const int base = wid * 8;  // tile-row of first tap for output row base+...
#define TLD(k, c) tile[(base + (k) * 4 + (c)) * TW + lane]
  float4 a0, a1, a2, a3, a4, a5, a6, a7, a8, a9, a10, a11;
  a0.x = TLD(0, 0);  a0.y = TLD(0, 1);  a0.z = TLD(0, 2);  a0.w = TLD(0, 3);
  a1.x = TLD(1, 0);  a1.y = TLD(1, 1);  a1.z = TLD(1, 2);  a1.w = TLD(1, 3);
  a2.x = TLD(2, 0);  a2.y = TLD(2, 1);  a2.z = TLD(2, 2);  a2.w = TLD(2, 3);
  a3.x = TLD(3, 0);  a3.y = TLD(3, 1);  a3.z = TLD(3, 2);  a3.w = TLD(3, 3);
  a4.x = TLD(4, 0);  a4.y = TLD(4, 1);  a4.z = TLD(4, 2);  a4.w = TLD(4, 3);
  a5.x = TLD(5, 0);  a5.y = TLD(5, 1);  a5.z = TLD(5, 2);  a5.w = TLD(5, 3);
  a6.x = TLD(6, 0);  a6.y = TLD(6, 1);  a6.z = TLD(6, 2);  a6.w = TLD(6, 3);
  a7.x = TLD(7, 0);  a7.y = TLD(7, 1);  a7.z = TLD(7, 2);  a7.w = TLD(7, 3);
  a8.x = TLD(8, 0);  a8.y = TLD(8, 1);  a8.z = TLD(8, 2);  a8.w = TLD(8, 3);
  a9.x = TLD(9, 0);  a9.y = TLD(9, 1);  a9.z = TLD(9, 2);  a9.w = TLD(9, 3);
  a10.x = TLD(10, 0); a10.y = TLD(10, 1); a10.z = TLD(10, 2); a10.w = TLD(10, 3);
  a11.x = TLD(11, 0); a11.y = TLD(11, 1); a11.z = TLD(11, 2); a11.w = TLD(11, 3);

  float4 r0, r1;
  r0.x = r0.y = r0.z = r0.w = 0.f;
  r1.x = r1.y = r1.z = r1.w = 0.f;
  CONV8(r0, r1)

  float* dst = ws + (size_t)ch * NHW + (size_t)(yb + base) * NW + x0 + lane;
  dst[0] = r0.x;
  dst[(size_t)NW] = r0.y;
  dst[2 * (size_t)NW] = r0.z;
  dst[3 * (size_t)NW] = r0.w;
  dst[4 * (size_t)NW] = r1.x;
  dst[5 * (size_t)NW] = r1.y;
  dst[6 * (size_t)NW] = r1.z;
  dst[7 * (size_t)NW] = r1.w;
}

// Pointwise 2x2 tensor algebra. ws planes: [0..6]=dY(ch), [7..13]=dX(ch).
__global__ __launch_bounds__(256) void k_final(
    const float* __restrict__ y, const float* __restrict__ v,
    const float* __restrict__ gds, const float* __restrict__ cadc,
    const float* __restrict__ myoc, const float* __restrict__ ws,
    const double* __restrict__ acc, float* __restrict__ out) {
  const size_t i = (size_t)blockIdx.x * blockDim.x + threadIdx.x;
  if (i >= NHW) return;

  const float m0 = (float)(acc[0] / (double)NHW);
  const float cad0 = fmaxf(cadc[0], 0.f);
  const float cad1 = fmaxf(cadc[1], 0.f);
  const float cad2 = fmaxf(cadc[2], 0.f);
  const float my0 = fmaxf(myoc[0], 0.f);
  const float my1 = fmaxf(myoc[1], 0.f);
  const float my2 = fmaxf(myoc[2], 0.f);
  const float my3 = fmaxf(myoc[3], 0.f);
  const float my4 = fmaxf(myoc[4], 0.f);

  const float m00 = y[i];
  const float m01 = y[i + (size_t)NHW];
  const float m10 = y[i + 2 * (size_t)NHW];
  const float m11 = y[i + 3 * (size_t)NHW];
  const float c = y[i + 4 * (size_t)NHW];
  const float v0 = v[i];
  const float v1 = v[i + (size_t)NHW];
  const float g = gds[i];

  const float dY_m00 = ws[i];
  const float dY_m01 = ws[i + (size_t)NHW];
  const float dY_m10 = ws[i + 2 * (size_t)NHW];
  const float dY_m11 = ws[i + 3 * (size_t)NHW];
  const float dY_c = ws[i + 4 * (size_t)NHW];
  const float dY_v0 = ws[i + 5 * (size_t)NHW];
  const float dY_v1 = ws[i + 6 * (size_t)NHW];
  const float dX_m00 = ws[i + 7 * (size_t)NHW];
  const float dX_m01 = ws[i + 8 * (size_t)NHW];
  const float dX_m10 = ws[i + 9 * (size_t)NHW];
  const float dX_m11 = ws[i + 10 * (size_t)NHW];
  const float dX_c = ws[i + 11 * (size_t)NHW];
  const float dX_v0 = ws[i + 12 * (size_t)NHW];
  const float dX_v1 = ws[i + 13 * (size_t)NHW];

  // gv[i][j] = d_j v_i ; j=0 -> Y, j=1 -> X
  const float gv00 = dY_v0, gv01 = dX_v0, gv10 = dY_v1, gv11 = dX_v1;
  const float ww = -0.5f * (gv01 - gv10);
  const float E00 = gv00, E11 = gv11;
  const float E01 = 0.5f * (gv01 + gv10);
  const float E10 = E01;

  const float trm = m00 + m11;
  const float dev00 = m00 - 0.5f * trm;
  const float dev01 = m01;
  const float dev10 = m10;
  const float dev11 = m11 - 0.5f * trm;
  const float dmag_sq = dev00 * dev00 + dev01 * dev01 + dev10 * dev10 + dev11 * dev11;
  const float dm = sqrtf(dmag_sq);
  const float dm2 = dm * dm;  // reference squares the sqrt
  const float devE = dev00 * E00 + dev01 * E01 + dev10 * E10 + dev11 * E11;
  const float sg = (devE > 0.f) ? 1.f : ((devE < 0.f) ? -1.f : 0.f);
  const float coef = sg * devE / dm2;
  const float sc = 0.5f * dm / m0;

  const float Ea00 = (E00 - coef * dev00) * sc;
  const float Ea01 = (E01 - coef * dev01) * sc;
  const float Ea10 = (E10 - coef * dev10) * sc;
  const float Ea11 = (E11 - coef * dev11) * sc;
  const float Ep00 = E00 - Ea00;
  const float Ep01 = E01 - Ea01;
  const float Ep10 = E10 - Ea10;
  const float Ep11 = E11 - Ea11;

  // mE = m*Ep + Ep*m
  const float mE00 = (m00 * Ep00 + m01 * Ep10) + (Ep00 * m00 + Ep01 * m10);
  const float mE01 = (m00 * Ep01 + m01 * Ep11) + (Ep00 * m01 + Ep01 * m11);
  const float mE10 = (m10 * Ep00 + m11 * Ep10) + (Ep10 * m00 + Ep11 * m10);
  const float mE11 = (m10 * Ep01 + m11 * Ep11) + (Ep10 * m01 + Ep11 * m11);

  const float divv = gv00 + gv11;
  const float cdot = -(v0 * dY_c + v1 * dX_c) - cad0 * c + cad1 * c * divv + cad2 * g;

  const float md00 = -(v0 * dY_m00 + v1 * dX_m00) - ww * m10 - ww * m01 - my0 * m00 +
                     my1 * mE00 - my2 * c * mE00 + my3 * trm + my4 * trm * m00;
  const float md01 = -(v0 * dY_m01 + v1 * dX_m01) - ww * m11 + ww * m00 - my0 * m01 +
                     my1 * mE01 - my2 * c * mE01 + my4 * trm * m01;
  const float md10 = -(v0 * dY_m10 + v1 * dX_m10) + ww * m00 - ww * m11 - my0 * m10 +
                     my1 * mE10 - my2 * c * mE10 + my4 * trm * m10;
  const float md11 = -(v0 * dY_m11 + v1 * dX_m11) + ww * m01 + ww * m10 - my0 * m11 +
                     my1 * mE11 - my2 * c * mE11 + my4 * trm * m11;

  out[i] = md00;
  out[i + (size_t)NHW] = md01;
  out[i + 2 * (size_t)NHW] = md10;
  out[i + 3 * (size_t)NHW] = md11;
  out[i + 4 * (size_t)NHW] = cdot;
}

extern "C" void kernel_launch(void* const* d_in, const int* in_sizes, int n_in,
                              void* d_out, int out_size, void* d_ws, size_t ws_size,
                              hipStream_t stream) {
  (void)in_sizes; (void)n_in; (void)out_size; (void)ws_size;
  const float* y = (const float*)d_in[0];
  const float* v = (const float*)d_in[1];
  const float* gds = (const float*)d_in[2];
  const float* cadc = (const float*)d_in[3];
  const float* myoc = (const float*)d_in[4];
  float* out = (float*)d_out;

  double* acc = (double*)d_ws;                       // 8B accumulator
  float* planes = (float*)((char*)d_ws + 512);       // 14 x NHW fp32 planes

  hipMemsetAsync(acc, 0, sizeof(double), stream);
  k_reduce<<<dim3(1024), dim3(256), 0, stream>>>(y, acc);
  k_dx<<<dim3(NH, 7), dim3(256), 0, stream>>>(y, v, planes);
  k_dy<<<dim3(NW / TW, NH / TH, 7), dim3(256), 0, stream>>>(y, v, planes);
  k_final<<<dim3(NHW / 256), dim3(256), 0, stream>>>(y, v, gds, cadc, myoc, planes, acc, out);
}

// Round 7
// 222.378 us; speedup vs baseline: 3.5328x; 3.0786x over previous
//
#include <hip/hip_runtime.h>
#include <math.h>

#define RAD 20
#define KLEN 41
#define NH 1024
#define NW 2048
#define NHW (NH * NW)

// ---- Compile-time Gaussian-derivative weights (fp64, matches numpy) ----
struct KW { float w[KLEN]; };
constexpr double cexp_neg(double u) {  // exp(-u), 0 <= u <= 0.5
  double term = 1.0, sum = 1.0;
  for (int k = 1; k < 30; ++k) { term *= (-u) / (double)k; sum += term; }
  return sum;
}
constexpr KW make_kw() {
  KW r{};
  double ph[KLEN] = {};
  double s = 0.0;
  for (int i = 0; i < KLEN; ++i) {
    double d = (double)(i - RAD);
    double e = cexp_neg(d * d / 800.0);
    e = e * e; e = e * e; e = e * e; e = e * e;  // ^16
    ph[i] = e; s += e;
  }
  for (int i = 0; i < KLEN; ++i) {
    double d = (double)(i - RAD);
    r.w[i] = (float)((-d / 25.0) * (ph[i] / s) / 2.27);
  }
  return r;
}
static constexpr KW KWC = make_kw();

// Tap-major conv core: window element k feeds outputs p in [k-40, min(7,k)]
// with literal weight w[k-p]. Live set stays ~1 chunk + 8 accs -> a minimal-
// register schedule is also the fast one (round-6 lesson: any structure whose
// live set exceeds the compiler's VGPR pick collapses into latency chains).
template <int K>
__device__ __forceinline__ void tap(float s, float& r0, float& r1, float& r2,
                                    float& r3, float& r4, float& r5, float& r6,
                                    float& r7) {
  if constexpr (K - 0 >= 0 && K - 0 <= 40) r0 = fmaf(s, KWC.w[K - 0], r0);
  if constexpr (K - 1 >= 0 && K - 1 <= 40) r1 = fmaf(s, KWC.w[K - 1], r1);
  if constexpr (K - 2 >= 0 && K - 2 <= 40) r2 = fmaf(s, KWC.w[K - 2], r2);
  if constexpr (K - 3 >= 0 && K - 3 <= 40) r3 = fmaf(s, KWC.w[K - 3], r3);
  if constexpr (K - 4 >= 0 && K - 4 <= 40) r4 = fmaf(s, KWC.w[K - 4], r4);
  if constexpr (K - 5 >= 0 && K - 5 <= 40) r5 = fmaf(s, KWC.w[K - 5], r5);
  if constexpr (K - 6 >= 0 && K - 6 <= 40) r6 = fmaf(s, KWC.w[K - 6], r6);
  if constexpr (K - 7 >= 0 && K - 7 <= 40) r7 = fmaf(s, KWC.w[K - 7], r7);
}

#define R8 r0, r1, r2, r3, r4, r5, r6, r7

template <int C>
__device__ __forceinline__ void chunk4(float4 a, float& r0, float& r1,
                                       float& r2, float& r3, float& r4,
                                       float& r5, float& r6, float& r7) {
  tap<4 * C + 0>(a.x, R8);
  tap<4 * C + 1>(a.y, R8);
  tap<4 * C + 2>(a.z, R8);
  tap<4 * C + 3>(a.w, R8);
}

// m_0 numerator: sum over pixels of ||m||_F (fp32 sqrt, fp64 accumulate).
__global__ __launch_bounds__(256) void k_reduce(const float* __restrict__ y,
                                                double* __restrict__ acc) {
  const int tid = blockIdx.x * blockDim.x + threadIdx.x;
  const int stride = gridDim.x * blockDim.x;
  double local = 0.0;
  for (int i = tid; i < NHW; i += stride) {
    float a = y[i];
    float b = y[i + NHW];
    float c = y[i + 2 * (size_t)NHW];
    float d = y[i + 3 * (size_t)NHW];
    local += (double)sqrtf(a * a + b * b + c * c + d * d);
  }
#pragma unroll
  for (int off = 32; off > 0; off >>= 1) local += __shfl_down(local, off, 64);
  __shared__ double smem[4];
  const int lane = threadIdx.x & 63;
  const int wid = threadIdx.x >> 6;
  if (lane == 0) smem[wid] = local;
  __syncthreads();
  if (threadIdx.x == 0) {
    double s = smem[0] + smem[1] + smem[2] + smem[3];
    atomicAdd(acc, s);
  }
}

// diffX, LDS-staged row + tap-major compute.
__global__ __launch_bounds__(256) void k_dx(const float* __restrict__ y,
                                            const float* __restrict__ v,
                                            float* __restrict__ ws) {
  __shared__ float row[NW + 2 * RAD];  // 2088 floats
  const int t = threadIdx.x;
  const int r = blockIdx.x;
  const int ch = blockIdx.y;  // 0..6 -> y0..y4, v0, v1
  const float* src = (ch < 5) ? (y + (size_t)ch * NHW) : (v + (size_t)(ch - 5) * NHW);
  const float* rp = src + (size_t)r * NW;

  // Stage: two dense 1KB wave loads + reflect halo.
  const float4* rp4 = (const float4*)rp;
  float4 b0 = rp4[t];
  float4 b1 = rp4[t + 256];
  float4* row4 = (float4*)(row + RAD);  // 80B offset, 16B-aligned
  row4[t] = b0;
  row4[t + 256] = b1;
  if (t < RAD) {
    row[t] = rp[RAD - t];                // left reflect (no edge repeat)
    row[NW + RAD + t] = rp[NW - 2 - t];  // right reflect
  }
  __syncthreads();

  // Outputs x0=8t..8t+7; window = padded row[8t..8t+47] = 12 float4 chunks,
  // consumed one at a time (tap-major).
  const float4* p = (const float4*)(row + 8 * t);
  float r0 = 0.f, r1 = 0.f, r2 = 0.f, r3 = 0.f;
  float r4 = 0.f, r5 = 0.f, r6 = 0.f, r7 = 0.f;
  chunk4<0>(p[0], R8);
  chunk4<1>(p[1], R8);
  chunk4<2>(p[2], R8);
  chunk4<3>(p[3], R8);
  chunk4<4>(p[4], R8);
  chunk4<5>(p[5], R8);
  chunk4<6>(p[6], R8);
  chunk4<7>(p[7], R8);
  chunk4<8>(p[8], R8);
  chunk4<9>(p[9], R8);
  chunk4<10>(p[10], R8);
  chunk4<11>(p[11], R8);

  float4 o0, o1;
  o0.x = r0; o0.y = r1; o0.z = r2; o0.w = r3;
  o1.x = r4; o1.y = r5; o1.z = r6; o1.w = r7;
  float4* dst = (float4*)(ws + (size_t)(7 + ch) * NHW + (size_t)r * NW + 8 * t);
  dst[0] = o0;
  dst[1] = o1;
}

#define TW 64  // k_dy tile width (x)
#define TH 32  // k_dy output rows per block

// diffY, LDS-staged tile + tap-major compute. Wrap applied at staging.
__global__ __launch_bounds__(256) void k_dy(const float* __restrict__ y,
                                            const float* __restrict__ v,
                                            float* __restrict__ ws) {
  __shared__ float tile[(TH + 2 * RAD) * TW];  // 72*64 floats = 18432B
  const int lane = threadIdx.x & 63;
  const int wid = threadIdx.x >> 6;  // 0..3
  const int x0 = blockIdx.x * TW;
  const int yb = blockIdx.y * TH;
  const int ch = blockIdx.z;
  const float* src = (ch < 5) ? (y + (size_t)ch * NHW) : (v + (size_t)(ch - 5) * NHW);

  // Stage 72 rows: 18 INDEPENDENT coalesced loads into named regs (one vmcnt
  // drain), then 18 LDS writes. Wave w stages rows w, w+4, ..., w+68.
#define GLD(k) src[(size_t)(((yb - RAD + wid + 4 * (k)) + NH) & (NH - 1)) * NW + x0 + lane]
  float t0 = GLD(0), t1 = GLD(1), t2 = GLD(2), t3 = GLD(3), t4 = GLD(4);
  float t5 = GLD(5), t6 = GLD(6), t7 = GLD(7), t8 = GLD(8), t9 = GLD(9);
  float t10 = GLD(10), t11 = GLD(11), t12 = GLD(12), t13 = GLD(13);
  float t14 = GLD(14), t15 = GLD(15), t16 = GLD(16), t17 = GLD(17);
#define TST(k, val) tile[(wid + 4 * (k)) * TW + lane] = val;
  TST(0, t0)  TST(1, t1)  TST(2, t2)  TST(3, t3)  TST(4, t4)  TST(5, t5)
  TST(6, t6)  TST(7, t7)  TST(8, t8)  TST(9, t9)  TST(10, t10) TST(11, t11)
  TST(12, t12) TST(13, t13) TST(14, t14) TST(15, t15) TST(16, t16) TST(17, t17)
  __syncthreads();

  // Wave w produces output rows yb+8w..yb+8w+7 at column x0+lane.
  // Window = tile rows base..base+47 (base=8w); consume 4 rows at a time.
  const int base = wid * 8;
  float r0 = 0.f, r1 = 0.f, r2 = 0.f, r3 = 0.f;
  float r4 = 0.f, r5 = 0.f, r6 = 0.f, r7 = 0.f;
#define DYCHUNK(c)                                                   \
  {                                                                  \
    float s0 = tile[(base + 4 * (c) + 0) * TW + lane];               \
    float s1 = tile[(base + 4 * (c) + 1) * TW + lane];               \
    float s2 = tile[(base + 4 * (c) + 2) * TW + lane];               \
    float s3 = tile[(base + 4 * (c) + 3) * TW + lane];               \
    tap<4 * (c) + 0>(s0, R8);                                        \
    tap<4 * (c) + 1>(s1, R8);                                        \
    tap<4 * (c) + 2>(s2, R8);                                        \
    tap<4 * (c) + 3>(s3, R8);                                        \
  }
  DYCHUNK(0) DYCHUNK(1) DYCHUNK(2) DYCHUNK(3) DYCHUNK(4) DYCHUNK(5)
  DYCHUNK(6) DYCHUNK(7) DYCHUNK(8) DYCHUNK(9) DYCHUNK(10) DYCHUNK(11)

  float* dst = ws + (size_t)ch * NHW + (size_t)(yb + base) * NW + x0 + lane;
  dst[0] = r0;
  dst[(size_t)NW] = r1;
  dst[2 * (size_t)NW] = r2;
  dst[3 * (size_t)NW] = r3;
  dst[4 * (size_t)NW] = r4;
  dst[5 * (size_t)NW] = r5;
  dst[6 * (size_t)NW] = r6;
  dst[7 * (size_t)NW] = r7;
}

// Pointwise 2x2 tensor algebra. ws planes: [0..6]=dY(ch), [7..13]=dX(ch).
__global__ __launch_bounds__(256) void k_final(
    const float* __restrict__ y, const float* __restrict__ v,
    const float* __restrict__ gds, const float* __restrict__ cadc,
    const float* __restrict__ myoc, const float* __restrict__ ws,
    const double* __restrict__ acc, float* __restrict__ out) {
  const size_t i = (size_t)blockIdx.x * blockDim.x + threadIdx.x;
  if (i >= NHW) return;

  const float m0 = (float)(acc[0] / (double)NHW);
  const float cad0 = fmaxf(cadc[0], 0.f);
  const float cad1 = fmaxf(cadc[1], 0.f);
  const float cad2 = fmaxf(cadc[2], 0.f);
  const float my0 = fmaxf(myoc[0], 0.f);
  const float my1 = fmaxf(myoc[1], 0.f);
  const float my2 = fmaxf(myoc[2], 0.f);
  const float my3 = fmaxf(myoc[3], 0.f);
  const float my4 = fmaxf(myoc[4], 0.f);

  const float m00 = y[i];
  const float m01 = y[i + (size_t)NHW];
  const float m10 = y[i + 2 * (size_t)NHW];
  const float m11 = y[i + 3 * (size_t)NHW];
  const float c = y[i + 4 * (size_t)NHW];
  const float v0 = v[i];
  const float v1 = v[i + (size_t)NHW];
  const float g = gds[i];

  const float dY_m00 = ws[i];
  const float dY_m01 = ws[i + (size_t)NHW];
  const float dY_m10 = ws[i + 2 * (size_t)NHW];
  const float dY_m11 = ws[i + 3 * (size_t)NHW];
  const float dY_c = ws[i + 4 * (size_t)NHW];
  const float dY_v0 = ws[i + 5 * (size_t)NHW];
  const float dY_v1 = ws[i + 6 * (size_t)NHW];
  const float dX_m00 = ws[i + 7 * (size_t)NHW];
  const float dX_m01 = ws[i + 8 * (size_t)NHW];
  const float dX_m10 = ws[i + 9 * (size_t)NHW];
  const float dX_m11 = ws[i + 10 * (size_t)NHW];
  const float dX_c = ws[i + 11 * (size_t)NHW];
  const float dX_v0 = ws[i + 12 * (size_t)NHW];
  const float dX_v1 = ws[i + 13 * (size_t)NHW];

  // gv[i][j] = d_j v_i ; j=0 -> Y, j=1 -> X
  const float gv00 = dY_v0, gv01 = dX_v0, gv10 = dY_v1, gv11 = dX_v1;
  const float ww = -0.5f * (gv01 - gv10);
  const float E00 = gv00, E11 = gv11;
  const float E01 = 0.5f * (gv01 + gv10);
  const float E10 = E01;

  const float trm = m00 + m11;
  const float dev00 = m00 - 0.5f * trm;
  const float dev01 = m01;
  const float dev10 = m10;
  const float dev11 = m11 - 0.5f * trm;
  const float dmag_sq = dev00 * dev00 + dev01 * dev01 + dev10 * dev10 + dev11 * dev11;
  const float dm = sqrtf(dmag_sq);
  const float dm2 = dm * dm;  // reference squares the sqrt
  const float devE = dev00 * E00 + dev01 * E01 + dev10 * E10 + dev11 * E11;
  const float sg = (devE > 0.f) ? 1.f : ((devE < 0.f) ? -1.f : 0.f);
  const float coef = sg * devE / dm2;
  const float sc = 0.5f * dm / m0;

  const float Ea00 = (E00 - coef * dev00) * sc;
  const float Ea01 = (E01 - coef * dev01) * sc;
  const float Ea10 = (E10 - coef * dev10) * sc;
  const float Ea11 = (E11 - coef * dev11) * sc;
  const float Ep00 = E00 - Ea00;
  const float Ep01 = E01 - Ea01;
  const float Ep10 = E10 - Ea10;
  const float Ep11 = E11 - Ea11;

  // mE = m*Ep + Ep*m
  const float mE00 = (m00 * Ep00 + m01 * Ep10) + (Ep00 * m00 + Ep01 * m10);
  const float mE01 = (m00 * Ep01 + m01 * Ep11) + (Ep00 * m01 + Ep01 * m11);
  const float mE10 = (m10 * Ep00 + m11 * Ep10) + (Ep10 * m00 + Ep11 * m10);
  const float mE11 = (m10 * Ep01 + m11 * Ep11) + (Ep10 * m01 + Ep11 * m11);

  const float divv = gv00 + gv11;
  const float cdot = -(v0 * dY_c + v1 * dX_c) - cad0 * c + cad1 * c * divv + cad2 * g;

  const float md00 = -(v0 * dY_m00 + v1 * dX_m00) - ww * m10 - ww * m01 - my0 * m00 +
                     my1 * mE00 - my2 * c * mE00 + my3 * trm + my4 * trm * m00;
  const float md01 = -(v0 * dY_m01 + v1 * dX_m01) - ww * m11 + ww * m00 - my0 * m01 +
                     my1 * mE01 - my2 * c * mE01 + my4 * trm * m01;
  const float md10 = -(v0 * dY_m10 + v1 * dX_m10) + ww * m00 - ww * m11 - my0 * m10 +
                     my1 * mE10 - my2 * c * mE10 + my4 * trm * m10;
  const float md11 = -(v0 * dY_m11 + v1 * dX_m11) + ww * m01 + ww * m10 - my0 * m11 +
                     my1 * mE11 - my2 * c * mE11 + my4 * trm * m11;

  out[i] = md00;
  out[i + (size_t)NHW] = md01;
  out[i + 2 * (size_t)NHW] = md10;
  out[i + 3 * (size_t)NHW] = md11;
  out[i + 4 * (size_t)NHW] = cdot;
}

extern "C" void kernel_launch(void* const* d_in, const int* in_sizes, int n_in,
                              void* d_out, int out_size, void* d_ws, size_t ws_size,
                              hipStream_t stream) {
  (void)in_sizes; (void)n_in; (void)out_size; (void)ws_size;
  const float* y = (const float*)d_in[0];
  const float* v = (const float*)d_in[1];
  const float* gds = (const float*)d_in[2];
  const float* cadc = (const float*)d_in[3];
  const float* myoc = (const float*)d_in[4];
  float* out = (float*)d_out;

  double* acc = (double*)d_ws;                       // 8B accumulator
  float* planes = (float*)((char*)d_ws + 512);       // 14 x NHW fp32 planes

  hipMemsetAsync(acc, 0, sizeof(double), stream);
  k_reduce<<<dim3(1024), dim3(256), 0, stream>>>(y, acc);
  k_dx<<<dim3(NH, 7), dim3(256), 0, stream>>>(y, v, planes);
  k_dy<<<dim3(NW / TW, NH / TH, 7), dim3(256), 0, stream>>>(y, v, planes);
  k_final<<<dim3(NHW / 256), dim3(256), 0, stream>>>(y, v, gds, cadc, myoc, planes, acc, out);
}